// Round 18
// baseline (365.533 us; speedup 1.0000x reference)
//
#include <hip/hip_runtime.h>
#include <cstdint>
#include <cstddef>

typedef unsigned long long u64;
typedef uint32_t u32;
typedef uint16_t u16;
typedef uint8_t u8;
typedef __attribute__((ext_vector_type(8))) short bf16x8;
typedef __attribute__((ext_vector_type(4))) float f32x4;

// ---------------------------------------------------------------------------
// Binary AlexNet-1D. bq(w)=0.1*sign(w), bact(x)=sign(x). All binary layers are
// exact integer XNOR-popcount + f64 affine epilogue. Activations bitpacked as
// [N][L][C/64] u64. Conv sum = CIN*K - 2*popc(a^w); maxpool (stride==kernel,
// scale 0.1>0) commutes with the affine map, so pool the integer sums.
// Layer 1 (real f32 input): bf16x2 split-precision MFMA GEMM (f32 sums exact
// to ~3e-6 << 1e-4 margin; near-zero outputs recomputed in f64 by fixup).
// Binary convs: block-cooperative LDS staging with COMPILE-TIME dims —
// zero-padded staging + guard-free popcount loop (all ds_read offsets are
// immediates; invalid positions are excluded only at the selection step).
// Layers 4..6 + fc1 + fc2 fused into one block-per-sample kernel (LDS).
// ---------------------------------------------------------------------------

#define CONV1_MARGIN 1e-4f

// -------------------- merged weight packing --------------------
struct PackJob { const float* src; u64* dst; int Cout, CIN, K, waveBase; };
struct PackJobs {
    PackJob j[6]; int totalWaves;
    const float* fw1; u32* fw1pk;
    const float* w1;  u16* wbf;
};

__global__ void pack_all_kernel(PackJobs P)
{
    int gtid = blockIdx.x * blockDim.x + threadIdx.x;
    int wid = gtid >> 6, lane = gtid & 63;
    if (wid < P.totalWaves) {
        int jj = 0;
        #pragma unroll
        for (int i = 1; i < 6; ++i) if (wid >= P.j[i].waveBase) jj = i;
        PackJob job = P.j[jj];
        int lw = wid - job.waveBase;
        int W = job.CIN >> 6;
        int wg = lw % W;
        int co = (lw / W) % job.Cout;
        int k  = lw / (W * job.Cout);
        int ci = wg * 64 + lane;
        bool sg = job.src[((size_t)co * job.CIN + ci) * job.K + k] >= 0.0f;
        u64 word = __ballot(sg);
        if (lane == 0) job.dst[lw] = word;
        return;
    }
    int idx = gtid - P.totalWaves * 64;
    if (idx < 512) {
        u32 wd = 0;
        #pragma unroll
        for (int i = 0; i < 32; ++i) wd |= (u32)(P.fw1[idx * 32 + i] >= 0.0f) << i;
        P.fw1pk[idx] = wd;
    }
    int j = idx - 512;
    if (j >= 0 && j < 256 * 192) {
        int co = j / 192, k = j - co * 192;
        int i = (k >= 96) ? (k - 96) : k;
        u16 val = 0;
        if (i < 69)
            val = (P.w1[(size_t)co * 69 + i] >= 0.0f) ? (u16)0x3F80 : (u16)0xBF80;
        P.wbf[(size_t)co * 192 + k] = val;
    }
}

// -------------------- layer 1: split-bf16 MFMA GEMM (v3) --------------------
// grid (n=128, T=31 strips of 80 conv-pos = 16 lp, ch=4 co-quarters of 64),
// block 256 = 4 waves; each wave owns one 16-co tile.
__global__ __launch_bounds__(256) void conv1_mfma_kernel(
    const float* __restrict__ x, const u16* __restrict__ wbf,
    const float* __restrict__ b, const float* __restrict__ sw,
    const float* __restrict__ sb,
    u64* __restrict__ opk64, u64* __restrict__ uflag64)
{
    __shared__ u32 xhl[3 * 236];       // (lo<<16)|hi per x sample of the strip
    __shared__ u32 Xb32[16 * 108];     // [pos][k-pair]; hi dwords 0..47, lo 48..95
    __shared__ float poolf[64 * 81];   // [co_loc][q] raw conv sums
    const int Lconv = 2406, Lin = 2560;
    int n = blockIdx.x, T = blockIdx.y, ch = blockIdx.z;
    int tid = threadIdx.x, lane = tid & 63, w = tid >> 6;
    int l0 = 80 * T - 2;

    // A-frags (weights): one 16-co tile per wave
    bf16x8 afr[6];
    {
        int cobase = 64 * ch + 16 * w;
        const u16* wp = wbf + (size_t)(cobase + (lane & 15)) * 192 + (lane >> 4) * 8;
        #pragma unroll
        for (int s = 0; s < 6; ++s)
            afr[s] = *(const bf16x8*)(wp + s * 32);
    }

    // phase 0: convert strip's x to packed bf16 hi/lo, once
    const float* xb = x + (size_t)n * 3 * Lin;
    #pragma unroll
    for (int e = 0; e < 3; ++e) {
        int idx = tid + 256 * e;
        if (idx < 3 * 236) {
            int ci = idx / 236, lrel = idx - ci * 236;
            int l = min(max(l0 + lrel, 0), Lin - 1);   // clamp: only invalid
            float xv = xb[ci * Lin + l];               // conv positions read it
            u32 ub = __float_as_uint(xv);
            u32 h = (ub + 0x7FFFu + ((ub >> 16) & 1u)) >> 16;   // RNE bf16
            float rem = xv - __uint_as_float(h << 16);
            u32 ur = __float_as_uint(rem);
            u32 lo = (ur + 0x7FFFu + ((ur >> 16) & 1u)) >> 16;
            xhl[idx] = (h & 0xFFFFu) | (lo << 16);
        }
    }
    __syncthreads();

    for (int j = 0; j < 5; ++j) {
        if (j) __syncthreads();
        #pragma unroll
        for (int e = 0; e < 3; ++e) {
            int s = tid + 256 * e;           // 0..767
            int p = s & 15, i2 = s >> 4;     // taps 2i2, 2i2+1
            u32 hiw = 0, low = 0;
            #pragma unroll
            for (int t2 = 0; t2 < 2; ++t2) {
                int t = 2 * i2 + t2;
                if (t < 69) {
                    int ci = (t < 23) ? 0 : ((t < 46) ? 1 : 2);
                    int kk = t - 23 * ci;
                    u32 v = xhl[ci * 236 + 16 * j + p + 7 * kk];
                    hiw |= (v & 0xFFFFu) << (16 * t2);
                    low |= (v >> 16) << (16 * t2);
                }
            }
            Xb32[p * 108 + i2] = hiw;
            Xb32[p * 108 + 48 + i2] = low;
        }
        __syncthreads();

        f32x4 acc = {0.0f, 0.0f, 0.0f, 0.0f};
        const u16* brow = (const u16*)Xb32 + (lane & 15) * 216 + (lane >> 4) * 8;
        #pragma unroll
        for (int s = 0; s < 6; ++s) {
            bf16x8 bf = *(const bf16x8*)(brow + s * 32);
            acc = __builtin_amdgcn_mfma_f32_16x16x32_bf16(afr[s], bf, acc, 0, 0, 0);
        }

        int q = 16 * j + (lane & 15);
        #pragma unroll
        for (int r = 0; r < 4; ++r) {
            int co_loc = 16 * w + (lane >> 4) * 4 + r;
            poolf[co_loc * 81 + q] = acc[r];
        }
    }
    __syncthreads();

    // epilogue: guarded pool + affine + sign + ballot-pack
    #pragma unroll
    for (int it = 0; it < 4; ++it) {
        int idx = tid + 256 * it;        // 0..1023
        int co_loc = idx & 63;           // == lane
        int lp_loc = idx >> 6;           // 0..15 (wave-uniform)
        int lp = 16 * T + lp_loc;
        int co = 64 * ch + co_loc;
        bool bit = false, unc = false;
        if (lp < 482) {
            float best = -1e30f;
            #pragma unroll
            for (int t = 0; t < 5; ++t) {
                int q = 5 * lp_loc + t;
                int l = l0 + q;
                if (l >= 0 && l < Lconv)
                    best = fmaxf(best, poolf[co_loc * 81 + q]);
            }
            float v = ((sw[co] >= 0.0f) ? 0.1f : -0.1f) * (0.1f * best + b[co]) + sb[co];
            bit = (v >= 0.0f);
            unc = (fabsf(v) < CONV1_MARGIN);
        }
        u64 wb = __ballot(bit);
        u64 wu = __ballot(unc);
        if (lp < 482 && lane == 0) {
            size_t widx = ((size_t)n * 482 + lp) * 4 + ch;
            opk64[widx] = wb;
            uflag64[widx] = wu;
        }
    }
}

// Fixup: thread per packed u64 word; recompute flagged channels in f64.
__global__ void conv1_fixup_kernel(const float* __restrict__ x,
                                   const float* __restrict__ w1,
                                   const float* __restrict__ b,
                                   const float* __restrict__ sw,
                                   const float* __restrict__ sb,
                                   const u64* __restrict__ uflag64,
                                   u64* __restrict__ opk64)
{
    int idx = blockIdx.x * blockDim.x + threadIdx.x;
    if (idx >= 128 * 482 * 4) return;
    u64 f = uflag64[idx];
    if (f == 0) return;
    int og = idx & 3;
    int lp = (idx >> 2) % 482;
    int n = idx / (4 * 482);
    u64 word = opk64[idx];
    const float* xb = x + (size_t)n * 3 * 2560;
    while (f) {
        int c = __ffsll(f) - 1;
        f &= f - 1;
        int co = og * 64 + c;
        const float* wp = w1 + (size_t)co * 69;
        double best = -1e300;
        for (int t = 0; t < 5; ++t) {
            int gl = 5 * lp - 2 + t;
            if (gl < 0 || gl >= 2406) continue;
            double s = 0.0;
            #pragma unroll
            for (int ci = 0; ci < 3; ++ci) {
                const float* xp = xb + ci * 2560 + gl;
                const float* wq = wp + ci * 23;
                #pragma unroll
                for (int kk = 0; kk < 23; ++kk) {
                    double xv = (double)xp[kk * 7];
                    s += (wq[kk] >= 0.0f) ? xv : -xv;
                }
            }
            best = fmax(best, s);
        }
        double v = ((sw[co] >= 0.0f) ? 0.1 : -0.1) * (0.1 * best + (double)b[co]) + (double)sb[co];
        u64 bit = (v >= 0.0) ? 1ull : 0ull;
        word = (word & ~(1ull << c)) | (bit << c);
    }
    opk64[idx] = word;
}

// ------- binary conv layers 2,3: LDS-staged, compile-time dims -------------
// block = (n, lp-group of LPW); 4 waves = 4 co-words. Activation rows staged
// (zero-padded) into LDS; popcount loop is guard-free with immediate offsets;
// invalid conv positions are excluded only at the selection step.
template<int K, int DIL, int PK, int PP, int W, int LPW, int LIN, int LCONV, int LOUT>
__global__ __launch_bounds__(256) void bconv_tpl_kernel(
    const u64* __restrict__ apk,  // [N][LIN][W]
    const u64* __restrict__ wpk,  // [K][Cout][W]
    const float* __restrict__ b,
    const float* __restrict__ sw,
    const float* __restrict__ sb,
    u64* __restrict__ opk,        // [N][LOUT][Cout/64]
    int Cout)
{
    constexpr int SPAN = (LPW * PK - 1) + (K - 1) * DIL + 1;
    __shared__ u64 sAct[SPAN * W];
    int n = blockIdx.x, lpg = blockIdx.y;
    int tid = threadIdx.x, lane = tid & 63, og = tid >> 6;
    int lp0 = lpg * LPW;
    int lbase = lp0 * PK - PP;
    int WOUT = Cout >> 6;
    int co = og * 64 + lane;

    const u64* ab = apk + (size_t)n * LIN * W;
    for (int i = tid; i < SPAN * W; i += 256) {
        int li = lbase + i / W;
        sAct[i] = (li >= 0 && li < LIN) ? ab[(size_t)li * W + (i % W)] : 0ull;
    }
    __syncthreads();

    int cnt[LPW][PK];
    #pragma unroll
    for (int j = 0; j < LPW; ++j)
        #pragma unroll
        for (int t = 0; t < PK; ++t) cnt[j][t] = 0;

    // guard-free: all sAct indices compile-time -> ds_read offset:imm
    #pragma unroll
    for (int k = 0; k < K; ++k) {
        u64 ww[W];
        #pragma unroll
        for (int w = 0; w < W; ++w)
            ww[w] = wpk[((size_t)k * Cout + co) * W + w];
        #pragma unroll
        for (int j = 0; j < LPW; ++j) {
            #pragma unroll
            for (int t = 0; t < PK; ++t) {
                const int ofs = (j * PK + t + k * DIL) * W;
                #pragma unroll
                for (int w = 0; w < W; ++w)
                    cnt[j][t] += __popcll(sAct[ofs + w] ^ ww[w]);
            }
        }
    }
    const int CINK = W * 64 * K;
    #pragma unroll
    for (int j = 0; j < LPW; ++j) {
        int lp = lp0 + j;
        int best = -2147483647;
        #pragma unroll
        for (int t = 0; t < PK; ++t) {
            int l = lp * PK - PP + t;            // wave-uniform guard (SALU)
            if (l < 0 || l >= LCONV) continue;
            int ksum = CINK - 2 * cnt[j][t];
            best = (ksum > best) ? ksum : best;
        }
        bool bit = false;
        if (lp < LOUT) {
            double conv = 0.1 * (double)best + (double)b[co];
            double v = ((sw[co] >= 0.0f) ? 0.1 : -0.1) * conv + (double)sb[co];
            bit = (v >= 0.0);
        }
        u64 word = __ballot(bit);
        if (lp < LOUT && lane == 0)
            opk[((size_t)n * LOUT + lp) * WOUT + og] = word;
    }
}

// -------------------- fused tail: layers 4,5,6 + fc1 + fc2 -----------------
__global__ __launch_bounds__(256) void tail_kernel(
    const u64* __restrict__ a3,
    const u64* __restrict__ wpk4,
    const u64* __restrict__ wpk5,
    const u64* __restrict__ wpk6,
    const float* __restrict__ b4, const float* __restrict__ sw4, const float* __restrict__ sb4,
    const float* __restrict__ b5, const float* __restrict__ sw5, const float* __restrict__ sb5,
    const float* __restrict__ b6, const float* __restrict__ sw6, const float* __restrict__ sb6,
    const u32* __restrict__ fw1pk,
    const float* __restrict__ fsw1, const float* __restrict__ fsb1,
    const u64* __restrict__ fpk2,
    const float* __restrict__ fsw2, const float* __restrict__ fsb2,
    float* __restrict__ out)
{
    __shared__ u64 sA[46 * 4];
    __shared__ u64 sB[42 * 4];
    __shared__ u64 sC[13 * 4];
    __shared__ u32 sA6;
    __shared__ u64 sH[8];
    int n = blockIdx.x, tid = threadIdx.x, lane = tid & 63, wv = tid >> 6;

    for (int i = tid; i < 46 * 4; i += 256) sA[i] = a3[(size_t)n * 46 * 4 + i];
    __syncthreads();

    {
        u64 ww[5][4];
        #pragma unroll
        for (int k = 0; k < 5; ++k)
            #pragma unroll
            for (int w = 0; w < 4; ++w)
                ww[k][w] = wpk4[((size_t)k * 256 + tid) * 4 + w];
        double bc = b4[tid];
        double swc = (sw4[tid] >= 0.0f) ? 0.1 : -0.1;
        double sbc = sb4[tid];
        for (int lp = 0; lp < 42; ++lp) {
            int cnt = 0;
            #pragma unroll
            for (int k = 0; k < 5; ++k)
                #pragma unroll
                for (int w = 0; w < 4; ++w)
                    cnt += __popcll(sA[(lp + k) * 4 + w] ^ ww[k][w]);
            int ksum = 256 * 5 - 2 * cnt;
            double v = swc * (0.1 * ksum + bc) + sbc;
            u64 word = __ballot(v >= 0.0);
            if (lane == 0) sB[lp * 4 + wv] = word;
        }
    }
    __syncthreads();

    {
        u64 ww[5][4];
        #pragma unroll
        for (int k = 0; k < 5; ++k)
            #pragma unroll
            for (int w = 0; w < 4; ++w)
                ww[k][w] = wpk5[((size_t)k * 256 + tid) * 4 + w];
        double bc = b5[tid];
        double swc = (sw5[tid] >= 0.0f) ? 0.1 : -0.1;
        double sbc = sb5[tid];
        for (int lp = 0; lp < 13; ++lp) {
            int best = -2147483647;
            #pragma unroll
            for (int t = 0; t < 3; ++t) {
                int l = 3 * lp - 1 + t;
                if (l < 0 || l >= 38) continue;
                int cnt = 0;
                #pragma unroll
                for (int k = 0; k < 5; ++k)
                    #pragma unroll
                    for (int w = 0; w < 4; ++w)
                        cnt += __popcll(sB[(l + k) * 4 + w] ^ ww[k][w]);
                int ksum = 256 * 5 - 2 * cnt;
                best = (ksum > best) ? ksum : best;
            }
            double v = swc * (0.1 * best + bc) + sbc;
            u64 word = __ballot(v >= 0.0);
            if (lane == 0) sC[lp * 4 + wv] = word;
        }
    }
    __syncthreads();

    if (tid < 32) {
        int co = tid >> 2, lp = tid & 3;
        int best = -2147483647;
        for (int t = 0; t < 3; ++t) {
            int l = 3 * lp - 1 + t;
            if (l < 0 || l >= 11) continue;
            int cnt = 0;
            #pragma unroll
            for (int k = 0; k < 3; ++k)
                #pragma unroll
                for (int w = 0; w < 4; ++w)
                    cnt += __popcll(sC[(l + k) * 4 + w] ^ wpk6[((size_t)k * 8 + co) * 4 + w]);
            int ksum = 256 * 3 - 2 * cnt;
            best = (ksum > best) ? ksum : best;
        }
        double v = ((sw6[co] >= 0.0f) ? 0.1 : -0.1) * (0.1 * best + (double)b6[co]) + (double)sb6[co];
        u64 word = __ballot(v >= 0.0);
        if (tid == 0) sA6 = (u32)word;
    }
    __syncthreads();

    {
        u32 a6w = sA6;
        #pragma unroll
        for (int p = 0; p < 2; ++p) {
            int o = tid + p * 256;
            int k = 32 - 2 * __popc(a6w ^ fw1pk[o]);
            double v = ((fsw1[o] >= 0.0f) ? 0.1 : -0.1) * (0.1 * (double)k) + (double)fsb1[o];
            u64 word = __ballot(v >= 0.0);
            if (lane == 0) sH[p * 4 + wv] = word;
        }
    }
    __syncthreads();

    {
        u64 h[8];
        #pragma unroll
        for (int w = 0; w < 8; ++w) h[w] = sH[w];
        #pragma unroll
        for (int p = 0; p < 4; ++p) {
            int o = tid + p * 256;
            if (o < 1000) {
                int cnt = 0;
                #pragma unroll
                for (int w = 0; w < 8; ++w)
                    cnt += __popcll(h[w] ^ fpk2[(size_t)o * 8 + w]);
                int k = 512 - 2 * cnt;
                double v = ((fsw2[o] >= 0.0f) ? 0.1 : -0.1) * (0.1 * (double)k) + (double)fsb2[o];
                out[(size_t)n * 1000 + o] = (float)v;
            }
        }
    }
}

extern "C" void kernel_launch(void* const* d_in, const int* in_sizes, int n_in,
                              void* d_out, int out_size, void* d_ws, size_t ws_size,
                              hipStream_t stream) {
    const float* x = (const float*)d_in[0];
    const float *w[6], *b[6], *sw[6], *sb[6];
    for (int i = 0; i < 6; ++i) {
        w[i]  = (const float*)d_in[1 + 4 * i];
        b[i]  = (const float*)d_in[2 + 4 * i];
        sw[i] = (const float*)d_in[3 + 4 * i];
        sb[i] = (const float*)d_in[4 + 4 * i];
    }
    const float* fw1  = (const float*)d_in[25];
    const float* fsw1 = (const float*)d_in[26];
    const float* fsb1 = (const float*)d_in[27];
    const float* fw2  = (const float*)d_in[28];
    const float* fsw2 = (const float*)d_in[29];
    const float* fsb2 = (const float*)d_in[30];
    float* out = (float*)d_out;
    (void)in_sizes; (void)n_in; (void)out_size; (void)ws_size;

    char* wsbase = (char*)d_ws;
    size_t off = 0;
    auto alloc = [&](size_t bytes) -> char* {
        char* p = wsbase + off;
        off = (off + bytes + 255) & ~(size_t)255;
        return p;
    };
    u64* wpk2 = (u64*)alloc((size_t)13 * 256 * 4 * 8);
    u64* wpk3 = (u64*)alloc((size_t)7 * 256 * 4 * 8);
    u64* wpk4 = (u64*)alloc((size_t)5 * 256 * 4 * 8);
    u64* wpk5 = (u64*)alloc((size_t)5 * 256 * 4 * 8);
    u64* wpk6 = (u64*)alloc((size_t)3 * 8 * 4 * 8);
    u64* fpk2 = (u64*)alloc((size_t)1000 * 8 * 8);
    u32* fw1pk = (u32*)alloc((size_t)512 * 4);
    u16* wbf = (u16*)alloc((size_t)256 * 192 * 2);
    u64* uflag64 = (u64*)alloc((size_t)128 * 482 * 4 * 8);
    u64* a1   = (u64*)alloc((size_t)128 * 482 * 4 * 8);
    u64* a2   = (u64*)alloc((size_t)128 * 149 * 4 * 8);
    u64* a3   = (u64*)alloc((size_t)128 * 46 * 4 * 8);

    const int BLK = 256;
    auto blocksForThreads = [](int n) { return dim3((unsigned)((n + 255) / 256)); };

    // merged weight packing (+ misc tail: fc1 masks, layer-1 bf16 weights)
    {
        PackJobs P;
        int base = 0;
        auto setJob = [&](int i, const float* src, u64* dst, int Cout, int CIN, int K) {
            P.j[i] = {src, dst, Cout, CIN, K, base};
            base += K * Cout * (CIN >> 6);
        };
        setJob(0, w[1], wpk2, 256, 256, 13);
        setJob(1, w[2], wpk3, 256, 256, 7);
        setJob(2, w[3], wpk4, 256, 256, 5);
        setJob(3, w[4], wpk5, 256, 256, 5);
        setJob(4, w[5], wpk6, 8, 256, 3);
        setJob(5, fw2, fpk2, 1000, 512, 1);
        P.totalWaves = base;
        P.fw1 = fw1; P.fw1pk = fw1pk; P.w1 = w[0]; P.wbf = wbf;
        int totalThreads = base * 64 + 512 + 256 * 192;
        pack_all_kernel<<<blocksForThreads(totalThreads), BLK, 0, stream>>>(P);
    }

    // layer 1: split-bf16 MFMA GEMM + f64 fixup of near-zero outputs
    conv1_mfma_kernel<<<dim3(128, 31, 4), BLK, 0, stream>>>(
        x, wbf, b[0], sw[0], sb[0], a1, uflag64);
    conv1_fixup_kernel<<<blocksForThreads(128 * 482 * 4), BLK, 0, stream>>>(
        x, w[0], b[0], sw[0], sb[0], uflag64, a1);

    // layer 2: K=13 dil=3 pool(3,1): Lin=482 Lconv=446 Lout=149
    bconv_tpl_kernel<13, 3, 3, 1, 4, 4, 482, 446, 149>
        <<<dim3(128, (149 + 3) / 4), BLK, 0, stream>>>(
            a1, wpk2, b[1], sw[1], sb[1], a2, 256);
    // layer 3: K=7 dil=2 pool(3,1): Lin=149 Lconv=137 Lout=46
    bconv_tpl_kernel<7, 2, 3, 1, 4, 4, 149, 137, 46>
        <<<dim3(128, (46 + 3) / 4), BLK, 0, stream>>>(
            a2, wpk3, b[2], sw[2], sb[2], a3, 256);
    // fused tail: layers 4,5,6 + fc1 + fc2
    tail_kernel<<<dim3(128), BLK, 0, stream>>>(
        a3, wpk4, wpk5, wpk6,
        b[3], sw[3], sb[3], b[4], sw[4], sb[4], b[5], sw[5], sb[5],
        fw1pk, fsw1, fsb1, fpk2, fsw2, fsb2, out);
}